// Round 5
// baseline (601.644 us; speedup 1.0000x reference)
//
#include <hip/hip_runtime.h>
#include <math.h>

#define DD 128
#define CAP 32
constexpr float EPS = 1e-5f;

typedef __bf16 bf16x8 __attribute__((ext_vector_type(8)));
typedef float  f32x4  __attribute__((ext_vector_type(4)));

__device__ __forceinline__ float4 ld4(const float* p){ return *(const float4*)p; }

__device__ __forceinline__ bf16x8 cvt8(const float* p){
  bf16x8 r;
#pragma unroll
  for (int i=0;i<8;i++) r[i] = (__bf16)p[i];
  return r;
}

// ---------- weight pre-pack: B-frag-major bf16, LANE-PERMUTED ----------
// tile tn, slot m=lane&15 holds output channel n = m*8 + tn  (so each lane's
// 8 accumulators are 8 consecutive channels -> vector epilogues everywhere)
__global__ __launch_bounds__(256)
void pack_w(const float* W0, const float* W1, const float* W2, const float* W3,
            const float* W4, const float* W5, const float* W6, const float* W7,
            __bf16* dst){
  int gidx = blockIdx.x*256 + threadIdx.x;
  int mat  = gidx >> 11;
  int i    = gidx & 2047;
  int lane = i & 63, frag = i >> 6;          // frag = tn*4+ks
  int tn = frag >> 2, ks = frag & 3;
  int n  = (lane & 15)*8 + tn;               // permuted column assignment
  int k0 = ks*32 + (lane >> 4)*8;
  const float* W;
  switch(mat){
    case 0: W=W0; break; case 1: W=W1; break; case 2: W=W2; break; case 3: W=W3; break;
    case 4: W=W4; break; case 5: W=W5; break; case 6: W=W6; break; default: W=W7; break;
  }
  __bf16* d = dst + (size_t)mat*16384 + (size_t)i*8;
#pragma unroll
  for (int j=0;j<8;j++) d[j] = (__bf16)W[(size_t)(k0+j)*DD + n];
}

// ---------- GroupNorm(1,128) in C-frag domain; lane's channels = m*8..m*8+7 ----------
template<bool RELU>
__device__ __forceinline__ void gn_frag(f32x4 (&acc)[8], const float* __restrict__ g,
                                        const float* __restrict__ b, int m){
  float gv[8], bv[8];
  *(float4*)gv     = ld4(g + m*8); *(float4*)(gv+4) = ld4(g + m*8 + 4);
  *(float4*)bv     = ld4(b + m*8); *(float4*)(bv+4) = ld4(b + m*8 + 4);
#pragma unroll
  for (int r=0;r<4;r++){
    float s=0.f, sq=0.f;
#pragma unroll
    for (int t=0;t<8;t++){ float v=acc[t][r]; s+=v; sq=fmaf(v,v,sq); }
#pragma unroll
    for (int mk=1; mk<16; mk<<=1){ s+=__shfl_xor(s,mk,64); sq+=__shfl_xor(sq,mk,64); }
    float mu=s*(1.f/DD);
    float rs=rsqrtf(sq*(1.f/DD)-mu*mu+EPS);
#pragma unroll
    for (int t=0;t<8;t++){
      float v=(acc[t][r]-mu)*rs*gv[t]+bv[t];
      if (RELU) v=fmaxf(v,0.f);
      acc[t][r]=v;
    }
  }
}

// ---------- MFMA: acc = A_frags @ Wp ----------
__device__ __forceinline__ void mfma_all(const bf16x8 (&af)[4], const __bf16* __restrict__ Wp,
                                         f32x4 (&acc)[8], int lane){
#pragma unroll
  for (int tn=0;tn<8;tn++){
    f32x4 a; a[0]=0.f; a[1]=0.f; a[2]=0.f; a[3]=0.f;
#pragma unroll
    for (int ks=0;ks<4;ks++){
      bf16x8 bf = *(const bf16x8*)(Wp + ((size_t)((tn*4+ks)*64 + lane))*8);
      a = __builtin_amdgcn_mfma_f32_16x16x32_bf16(af[ks], bf, a, 0,0,0);
    }
    acc[tn]=a;
  }
}

__device__ __forceinline__ void read_af(const __bf16* T, bf16x8 (&af)[4], int w, int lane){
  int m=lane&15, q=lane>>4;
#pragma unroll
  for (int ks=0;ks<4;ks++)
    af[ks] = *(const bf16x8*)(T + (16*w+m)*136 + ks*32 + q*8);
}

// C-frag -> LDS tile, one ds_write_b128 per row (channels m*8..m*8+7)
__device__ __forceinline__ void write_cfrag_bf16(__bf16* T, const f32x4 (&acc)[8], int w, int lane){
  int m=lane&15, q=lane>>4;
#pragma unroll
  for (int r=0;r<4;r++){
    int row=16*w+4*q+r;
    bf16x8 v;
#pragma unroll
    for (int t=0;t<8;t++) v[t]=(__bf16)acc[t][r];
    *(bf16x8*)(T + row*136 + m*8) = v;
  }
}

// C-frag -> global bf16, vectorized
__device__ __forceinline__ void st_c_bf16(__bf16* Y, const f32x4 (&acc)[8], int rowBase,
                                          int w, int q, int m, int M){
#pragma unroll
  for (int r=0;r<4;r++){
    int row = rowBase + 16*w + 4*q + r;
    if (row < M){
      bf16x8 v;
#pragma unroll
      for (int t=0;t<8;t++) v[t]=(__bf16)acc[t][r];
      *(bf16x8*)(Y + (size_t)row*DD + m*8) = v;
    }
  }
}

// C-frag -> global f32, vectorized
__device__ __forceinline__ void st_c_f32(float* Y, const f32x4 (&acc)[8], int rowBase,
                                         int w, int q, int m, int M){
#pragma unroll
  for (int r=0;r<4;r++){
    int row = rowBase + 16*w + 4*q + r;
    if (row < M){
      float4 a0 = make_float4(acc[0][r],acc[1][r],acc[2][r],acc[3][r]);
      float4 a1 = make_float4(acc[4][r],acc[5][r],acc[6][r],acc[7][r]);
      *(float4*)(Y + (size_t)row*DD + m*8)     = a0;
      *(float4*)(Y + (size_t)row*DD + m*8 + 4) = a1;
    }
  }
}

__device__ __forceinline__ void load_af_f32(const float* X, bf16x8 (&af)[4], int row, int M, int q){
  if (row < M){
    const float* xr = X + (size_t)row*DD;
#pragma unroll
    for (int ks=0;ks<4;ks++){
      float t[8];
      *(float4*)t     = ld4(xr + ks*32 + q*8);
      *(float4*)(t+4) = ld4(xr + ks*32 + q*8 + 4);
      af[ks] = cvt8(t);
    }
  } else {
#pragma unroll
    for (int ks=0;ks<4;ks++){
#pragma unroll
      for (int j=0;j<8;j++) af[ks][j]=(__bf16)0.f;
    }
  }
}

// ---------- prep: [bucket build] + [Q->Aq2 (+base)] + [Cc] ----------
__global__ __launch_bounds__(256)
void prep_kernel(const int* __restrict__ hi, int E, int* __restrict__ counts, int* __restrict__ perm,
                 const float* __restrict__ agts,
                 const __bf16* __restrict__ Wp_q, const float* __restrict__ g_q, const float* __restrict__ b_q,
                 const __bf16* __restrict__ Wp_mid, const __bf16* __restrict__ Wp_agt,
                 __bf16* __restrict__ Aq2bf, float* __restrict__ baseF, int nA,
                 const float* __restrict__ ctx, const __bf16* __restrict__ Wp_chi,
                 __bf16* __restrict__ Ccbf, int nC,
                 int gBucket, int gA){
  __shared__ __bf16 T[64*136];
  int b = blockIdx.x;
  if (b < gBucket){
    int e = b*256 + threadIdx.x;
    if (e < E){
      int a = hi[e];
      int slot = atomicAdd(&counts[a], 1);
      if (slot < CAP) perm[(size_t)a*CAP + slot] = e;
    }
    return;
  }
  b -= gBucket;
  int tid=threadIdx.x, w=tid>>6, lane=tid&63, m=lane&15, q=lane>>4;
  if (b < gA){
    int rowA = b*64 + 16*w + m;
    bf16x8 af_a[4];
    load_af_f32(agts, af_a, rowA, nA, q);
    f32x4 acc[8];
    mfma_all(af_a, Wp_q, acc, lane);
    gn_frag<true>(acc, g_q, b_q, m);
    write_cfrag_bf16(T, acc, w, lane);
    bf16x8 af_q[4];
    read_af(T, af_q, w, lane);               // same-wave ordered
    mfma_all(af_q, Wp_mid, acc, lane);
    st_c_bf16(Aq2bf, acc, b*64, w, q, m, nA);
    if (baseF){
      mfma_all(af_a, Wp_agt, acc, lane);
      st_c_f32(baseF, acc, b*64, w, q, m, nA);
    }
  } else {
    int bid = b - gA;
    bf16x8 af[4];
    load_af_f32(ctx, af, bid*64 + 16*w + m, nC, q);
    f32x4 acc[8];
    mfma_all(af, Wp_chi, acc, lane);
    st_c_bf16(Ccbf, acc, bid*64, w, q, m, nC);
  }
}

// ---------- fused edge kernel: 64 edges/block, ZERO barriers ----------
__global__ __launch_bounds__(256)
void edge_kernel(const float* __restrict__ agt_ctrs, const float* __restrict__ ctx_ctrs,
                 const int* __restrict__ hi, const int* __restrict__ wi,
                 const float* __restrict__ W1, const float* __restrict__ B1,
                 const __bf16* __restrict__ Wp_d2, const float* __restrict__ g_dist, const float* __restrict__ b_dist,
                 const __bf16* __restrict__ Wp_c1, const float* __restrict__ g_c1, const float* __restrict__ b_c1,
                 const __bf16* __restrict__ Wp_c2,
                 const __bf16* __restrict__ Aq2, const __bf16* __restrict__ Cc,
                 float* __restrict__ accOut, __bf16* __restrict__ edge_out, int E){
  __shared__ __bf16 T[64*136];
  int tid=threadIdx.x, w=tid>>6, lane=tid&63, m=lane&15, q=lane>>4;
  int eBase = blockIdx.x*64;
  // ---- gather prefetch (band-local rows: grow in [16w,16w+16)) ----
  int grow = tid>>2, gch = tid&3;
  int ge = eBase + grow;
  int ghe=0, gwe=0;
  if (ge < E){ ghe = hi[ge]; gwe = wi[ge]; }
  bf16x8 ga[4], gc[4];
  {
    const __bf16* ap = Aq2 + (size_t)ghe*DD + gch*32;
    const __bf16* cp = Cc  + (size_t)gwe*DD + gch*32;
#pragma unroll
    for (int c2=0;c2<4;c2++){ ga[c2]=*(const bf16x8*)(ap+c2*8); gc[c2]=*(const bf16x8*)(cp+c2*8); }
  }
  // ---- stage0 (band-local): lane covers edge 16w+(lane&15), channels q*32.. ----
  {
    int er = m;
    int e = eBase + 16*w + er;
    float dx=0.f, dy=0.f;
    if (e < E){
      int h0=hi[e], w0=wi[e];
      dx = agt_ctrs[2*h0]   - ctx_ctrs[2*w0];
      dy = agt_ctrs[2*h0+1] - ctx_ctrs[2*w0+1];
    }
#pragma unroll
    for (int s=0;s<4;s++){
      int c0 = q*32 + s*8;
      float wa[8], wb[8], bb[8], t[8];
      *(float4*)wa = ld4(W1+c0);    *(float4*)(wa+4) = ld4(W1+c0+4);
      *(float4*)wb = ld4(W1+DD+c0); *(float4*)(wb+4) = ld4(W1+DD+c0+4);
      *(float4*)bb = ld4(B1+c0);    *(float4*)(bb+4) = ld4(B1+c0+4);
#pragma unroll
      for (int j=0;j<8;j++)
        t[j] = fmaxf(fmaf(dx, wa[j], fmaf(dy, wb[j], bb[j])), 0.f);
      *(bf16x8*)(T + (16*w+er)*136 + c0) = cvt8(t);
    }
  }
  bf16x8 af[4]; f32x4 acc[8];
  // ---- stage1: d = relu(gn(d1 @ W_dist2)) ----
  read_af(T, af, w, lane);
  mfma_all(af, Wp_d2, acc, lane);
  gn_frag<true>(acc, g_dist, b_dist, m);
  write_cfrag_bf16(T, acc, w, lane);
  // ---- stage2: c = relu(gn(d @ W_c1lo + Aq2[hi] + Cc[wi])) ----
  read_af(T, af, w, lane);
  // overwrite own band rows with gather sums (after frag reads; same-wave ordered)
#pragma unroll
  for (int c2=0;c2<4;c2++){
    float s[8];
#pragma unroll
    for (int j=0;j<8;j++) s[j] = (float)ga[c2][j] + (float)gc[c2][j];
    *(bf16x8*)(T + grow*136 + gch*32 + c2*8) = cvt8(s);
  }
  mfma_all(af, Wp_c1, acc, lane);
#pragma unroll
  for (int r=0;r<4;r++){
    int row = 16*w + 4*q + r;
    bf16x8 tv = *(const bf16x8*)(T + row*136 + m*8);
#pragma unroll
    for (int t=0;t<8;t++) acc[t][r] += (float)tv[t];
  }
  gn_frag<true>(acc, g_c1, b_c1, m);
  write_cfrag_bf16(T, acc, w, lane);
  // ---- stage3: e_out = c @ W_c2 ; direct vector store ----
  read_af(T, af, w, lane);
  mfma_all(af, Wp_c2, acc, lane);
  if (edge_out){
#pragma unroll
    for (int r=0;r<4;r++){
      int erow = eBase + 16*w + 4*q + r;
      if (erow < E){
        bf16x8 v;
#pragma unroll
        for (int t=0;t<8;t++) v[t]=(__bf16)acc[t][r];
        *(bf16x8*)(edge_out + (size_t)erow*DD + m*8) = v;
      }
    }
  } else {
#pragma unroll
    for (int r=0;r<4;r++){
      int row = 16*w + 4*q + r;
      if (eBase + row < E){
        int he = hi[eBase + row];
        float* dst = accOut + (size_t)he*DD + m*8;
#pragma unroll
        for (int t=0;t<8;t++)
          atomicAdd(dst + t, acc[t][r]);
      }
    }
  }
}

// ---------- path-A final: base MFMA + edge gather-sum + GN chain + residual (no barriers) ----------
__global__ __launch_bounds__(256)
void final_fused(const float* __restrict__ agts, const __bf16* __restrict__ Wp_agt,
                 const int* __restrict__ counts, const int* __restrict__ perm,
                 const __bf16* __restrict__ edge_out,
                 const float* __restrict__ g_n, const float* __restrict__ b_n,
                 const __bf16* __restrict__ Wp_lin, const float* __restrict__ g_lin, const float* __restrict__ b_lin,
                 float* __restrict__ out, int M){
  __shared__ __bf16 T[64*136];
  int tid=threadIdx.x, w=tid>>6, lane=tid&63, m=lane&15, q=lane>>4;
  int rowBase=blockIdx.x*64;
  // base = agts @ W_agt -> bf16 C-frags in T (band-local)
  bf16x8 af_a[4];
  load_af_f32(agts, af_a, rowBase + 16*w + m, M, q);
  f32x4 acc[8];
  mfma_all(af_a, Wp_agt, acc, lane);
  write_cfrag_bf16(T, acc, w, lane);
  // gather phase: 4 lanes per row (band-local rows)
  int grow=tid>>2, gch=tid&3;
  int a = rowBase + grow;
  float s[32];
#pragma unroll
  for (int c2=0;c2<4;c2++){
    bf16x8 bv = *(const bf16x8*)(T + grow*136 + gch*32 + c2*8);
#pragma unroll
    for (int k=0;k<8;k++) s[c2*8+k] = (float)bv[k];
  }
  int cnt = 0;
  if (a < M){ cnt = counts[a]; cnt = cnt < CAP ? cnt : CAP; }
  for (int j=0;j<cnt;j++){
    int e = perm[(size_t)a*CAP + j];
    const __bf16* ep = edge_out + (size_t)e*DD + gch*32;
#pragma unroll
    for (int c2=0;c2<4;c2++){
      bf16x8 v = *(const bf16x8*)(ep + c2*8);
#pragma unroll
      for (int k=0;k<8;k++) s[c2*8+k] += (float)v[k];
    }
  }
  // GN + ReLU over the row (4-lane reduction)
  {
    float sm=0.f, sq=0.f;
#pragma unroll
    for (int k=0;k<32;k++){ sm+=s[k]; sq=fmaf(s[k],s[k],sq); }
    sm+=__shfl_xor(sm,1,64); sm+=__shfl_xor(sm,2,64);
    sq+=__shfl_xor(sq,1,64); sq+=__shfl_xor(sq,2,64);
    float mu=sm*(1.f/DD), rs=rsqrtf(sq*(1.f/DD)-mu*mu+EPS);
    float gv[32], bv[32];
#pragma unroll
    for (int c2=0;c2<8;c2++){
      *(float4*)(gv+c2*4) = ld4(g_n + gch*32 + c2*4);
      *(float4*)(bv+c2*4) = ld4(b_n + gch*32 + c2*4);
    }
#pragma unroll
    for (int k=0;k<32;k++)
      s[k]=fmaxf((s[k]-mu)*rs*gv[k]+bv[k],0.f);
  }
#pragma unroll
  for (int c2=0;c2<4;c2++)
    *(bf16x8*)(T + grow*136 + gch*32 + c2*8) = cvt8(s + c2*8);
  // W_lin MFMA + GN + residual + ReLU (vector epilogue)
  bf16x8 af[4];
  read_af(T, af, w, lane);
  mfma_all(af, Wp_lin, acc, lane);
  gn_frag<false>(acc, g_lin, b_lin, m);
#pragma unroll
  for (int r=0;r<4;r++){
    int row=rowBase+16*w+4*q+r;
    if (row<M){
      float rr[8];
      *(float4*)rr     = ld4(agts + (size_t)row*DD + m*8);
      *(float4*)(rr+4) = ld4(agts + (size_t)row*DD + m*8 + 4);
      float4 o0 = make_float4(fmaxf(acc[0][r]+rr[0],0.f), fmaxf(acc[1][r]+rr[1],0.f),
                              fmaxf(acc[2][r]+rr[2],0.f), fmaxf(acc[3][r]+rr[3],0.f));
      float4 o1 = make_float4(fmaxf(acc[4][r]+rr[4],0.f), fmaxf(acc[5][r]+rr[5],0.f),
                              fmaxf(acc[6][r]+rr[6],0.f), fmaxf(acc[7][r]+rr[7],0.f));
      *(float4*)(out + (size_t)row*DD + m*8)     = o0;
      *(float4*)(out + (size_t)row*DD + m*8 + 4) = o1;
    }
  }
}

// ---------- path-B final (atomic fallback) ----------
__global__ __launch_bounds__(256)
void final_kernel(const float* __restrict__ accF, const float* __restrict__ g_n, const float* __restrict__ b_n,
                  const __bf16* __restrict__ Wp_lin, const float* __restrict__ g_lin, const float* __restrict__ b_lin,
                  const float* __restrict__ res, float* __restrict__ out, int M){
  __shared__ __bf16 Ab[64*136];
  int tid=threadIdx.x, w=tid>>6, lane=tid&63, m=lane&15, q=lane>>4;
  int rowBase=blockIdx.x*64;
  {
    int rl=tid>>2, qq=tid&3;
    int row=rowBase+rl;
    float v[32];
    float s=0.f, sq=0.f;
#pragma unroll
    for (int t8=0;t8<8;t8++){
      float4 x=make_float4(0.f,0.f,0.f,0.f);
      if (row<M) x=ld4(accF + (size_t)row*DD + qq*32 + t8*4);
      v[t8*4]=x.x; v[t8*4+1]=x.y; v[t8*4+2]=x.z; v[t8*4+3]=x.w;
      s  += x.x+x.y+x.z+x.w;
      sq += x.x*x.x+x.y*x.y+x.z*x.z+x.w*x.w;
    }
    s+=__shfl_xor(s,1,64); s+=__shfl_xor(s,2,64);
    sq+=__shfl_xor(sq,1,64); sq+=__shfl_xor(sq,2,64);
    float mu=s*(1.f/DD), rs=rsqrtf(sq*(1.f/DD)-mu*mu+EPS);
#pragma unroll
    for (int j=0;j<32;j++){
      int c=qq*32+j;
      v[j]=fmaxf((v[j]-mu)*rs*g_n[c]+b_n[c],0.f);
    }
#pragma unroll
    for (int s2=0;s2<4;s2++)
      *(bf16x8*)(Ab + rl*136 + qq*32 + s2*8) = cvt8(v+s2*8);
  }
  __syncthreads();
  bf16x8 af[4]; f32x4 acc[8];
  read_af(Ab, af, w, lane);
  mfma_all(af, Wp_lin, acc, lane);
  gn_frag<false>(acc, g_lin, b_lin, m);
#pragma unroll
  for (int r=0;r<4;r++){
    int row=rowBase+16*w+4*q+r;
    if (row<M){
      float rr[8];
      *(float4*)rr     = ld4(res + (size_t)row*DD + m*8);
      *(float4*)(rr+4) = ld4(res + (size_t)row*DD + m*8 + 4);
      float4 o0 = make_float4(fmaxf(acc[0][r]+rr[0],0.f), fmaxf(acc[1][r]+rr[1],0.f),
                              fmaxf(acc[2][r]+rr[2],0.f), fmaxf(acc[3][r]+rr[3],0.f));
      float4 o1 = make_float4(fmaxf(acc[4][r]+rr[4],0.f), fmaxf(acc[5][r]+rr[5],0.f),
                              fmaxf(acc[6][r]+rr[6],0.f), fmaxf(acc[7][r]+rr[7],0.f));
      *(float4*)(out + (size_t)row*DD + m*8)     = o0;
      *(float4*)(out + (size_t)row*DD + m*8 + 4) = o1;
    }
  }
}

extern "C" void kernel_launch(void* const* d_in, const int* in_sizes, int n_in,
                              void* d_out, int out_size, void* d_ws, size_t ws_size,
                              hipStream_t stream){
  const float* agts     = (const float*)d_in[0];
  const float* ctx      = (const float*)d_in[1];
  const float* agt_ctrs = (const float*)d_in[2];
  const float* ctx_ctrs = (const float*)d_in[3];
  const float* W_dist1  = (const float*)d_in[4];
  const float* b_dist1  = (const float*)d_in[5];
  const float* W_dist2  = (const float*)d_in[6];
  const float* g_dist   = (const float*)d_in[7];
  const float* b_dist   = (const float*)d_in[8];
  const float* W_q      = (const float*)d_in[9];
  const float* g_q      = (const float*)d_in[10];
  const float* b_q      = (const float*)d_in[11];
  const float* W_c1     = (const float*)d_in[12];
  const float* g_c1     = (const float*)d_in[13];
  const float* b_c1     = (const float*)d_in[14];
  const float* W_c2     = (const float*)d_in[15];
  const float* W_agt    = (const float*)d_in[16];
  const float* g_n      = (const float*)d_in[17];
  const float* b_n      = (const float*)d_in[18];
  const float* W_lin    = (const float*)d_in[19];
  const float* g_lin    = (const float*)d_in[20];
  const float* b_lin    = (const float*)d_in[21];
  const int*   hi       = (const int*)d_in[22];
  const int*   wi       = (const int*)d_in[23];

  int nA = in_sizes[0]/DD, nC = in_sizes[1]/DD, nE = in_sizes[22];
  float* out = (float*)d_out;

  auto al = [](size_t x){ return (x + 255) & ~(size_t)255; };
  size_t oAq2 = 0;
  size_t oCc  = al(oAq2 + (size_t)nA*DD*2);
  size_t oWp  = al(oCc  + (size_t)nC*DD*2);
  size_t oCnt = al(oWp  + (size_t)8*16384*2);
  size_t oPerm= al(oCnt + (size_t)nA*4);
  size_t oTail= al(oPerm+ (size_t)nA*CAP*4);
  size_t needA = oTail + (size_t)nE*DD*2;   // edge_out
  bool bigA = (ws_size >= needA);

  char* ws = (char*)d_ws;
  __bf16* Aq2bf = (__bf16*)(ws + oAq2);
  __bf16* Ccbf  = (__bf16*)(ws + oCc);
  __bf16* Wp    = (__bf16*)(ws + oWp);
  int*    counts= (int*)   (ws + oCnt);
  int*    perm  = (int*)   (ws + oPerm);
  __bf16* edge_out = (__bf16*)(ws + oTail);
  float*  CF    = (float*)(ws + oCnt);      // path-B only

  dim3 B(256);
  int gA=(nA+63)/64, gC=(nC+63)/64, gE=(nE+63)/64;
  int gBucket = bigA ? (nE+255)/256 : 0;

  // pack: 0=W_dist2 1=W_c1lo 2=W_c2 3=W_q 4=W_c1mid 5=W_c1hi 6=W_agt 7=W_lin
  pack_w<<<64,B,0,stream>>>(W_dist2, W_c1, W_c2, W_q,
                            W_c1+128*DD, W_c1+256*DD, W_agt, W_lin, Wp);
  if (bigA){
    hipMemsetAsync(counts, 0, (size_t)nA*4, stream);
    prep_kernel<<<gBucket+gA+gC,B,0,stream>>>(hi, nE, counts, perm,
        agts, Wp+3*16384, g_q, b_q, Wp+4*16384, Wp+6*16384, Aq2bf, nullptr, nA,
        ctx, Wp+5*16384, Ccbf, nC, gBucket, gA);
    edge_kernel<<<gE,B,0,stream>>>(agt_ctrs, ctx_ctrs, hi, wi,
        W_dist1, b_dist1, Wp+0, g_dist, b_dist,
        Wp+1*16384, g_c1, b_c1, Wp+2*16384,
        Aq2bf, Ccbf, nullptr, edge_out, nE);
    final_fused<<<gA,B,0,stream>>>(agts, Wp+6*16384, counts, perm, edge_out,
        g_n, b_n, Wp+7*16384, g_lin, b_lin, out, nA);
  } else {
    prep_kernel<<<gA+gC,B,0,stream>>>(hi, nE, counts, perm,
        agts, Wp+3*16384, g_q, b_q, Wp+4*16384, Wp+6*16384, Aq2bf, CF, nA,
        ctx, Wp+5*16384, Ccbf, nC, 0, gA);
    edge_kernel<<<gE,B,0,stream>>>(agt_ctrs, ctx_ctrs, hi, wi,
        W_dist1, b_dist1, Wp+0, g_dist, b_dist,
        Wp+1*16384, g_c1, b_c1, Wp+2*16384,
        Aq2bf, Ccbf, CF, nullptr, nE);
    final_kernel<<<gA,B,0,stream>>>(CF, g_n, b_n, Wp+7*16384, g_lin, b_lin, agts, out, nA);
  }
}